// Round 5
// baseline (68.496 us; speedup 1.0000x reference)
//
#include <hip/hip_runtime.h>

// FinalLayer: out[b,m] = bias + sum_c w_c * sum_n y[b,n,c] * exp(-0.5*(x_n-t_m)^2 * exp(-2*sigma_c))
// Shapes: x(B,N_IN) y(B,N_IN,C) t(B,N_OUT) sigma(C) w(C) b(1); out flat B*N_OUT fp32.
//
// sigma is channel-uniform for these inputs -> exact factorization:
//   out[b,m] = bias + sum_n ytil[b,n] * exp2(-((x_n - t_m)*s)^2),
//   ytil[b,n] = sum_c w_c y[b,n,c],  s^2 = 0.5*log2(e)*exp(-2*sigma0)
// SINGLE dispatch: each block recomputes ytil for its batch into LDS
// (~0.2 us, 64x redundant but L2-hot), then does its m-tile. No serial
// graph-node chain, no atomics, no memset. Uniformity checked on-device
// (__ballot); correct per-channel fallback kept for general sigma.
constexpr int Bb   = 4;
constexpr int NIN  = 512;
constexpr int NOUT = 1024;
constexpr int CC   = 64;    // == wavefront size

constexpr int MTILE = 16;           // m per block
constexpr int NGRP  = 16;           // internal n-split
constexpr int NPER  = NIN / NGRP;   // 32
constexpr int MBLKS = NOUT / MTILE; // 64 m-tiles per batch; grid = 4*64 = 256

__global__ __launch_bounds__(256) void rbf_fused(
    const float* __restrict__ x,     const float* __restrict__ y,
    const float* __restrict__ t,     const float* __restrict__ sigma,
    const float* __restrict__ w,     const float* __restrict__ bias,
    float* __restrict__ out)
{
    __shared__ float ytil_s[NIN];          // 2 KB
    __shared__ float xs_s[NIN];            // 2 KB
    __shared__ float red[64];              // wave partials

    const int tid  = threadIdx.x;
    const int lane = tid & 63;
    const int wv   = tid >> 6;
    const int mt   = blockIdx.x & (MBLKS - 1);
    const int b    = blockIdx.x >> 6;

    const float s0  = sigma[0];
    const bool  uni = (__ballot(sigma[lane] == s0) == ~0ull);  // block-consistent

    if (uni) {
        // s = sqrt(0.5*log2(e))*exp(-sigma0)
        const float s = 0.84932180f * __expf(-s0);

        // ---- phase 1: ytil + x*s into LDS (2 n's per thread, float4 dots)
        const float4* __restrict__ w4 = (const float4*)w;
#pragma unroll
        for (int r = 0; r < 2; ++r) {
            const int n = r * 256 + tid;
            const float4* __restrict__ y4 = (const float4*)(y + ((size_t)b * NIN + n) * CC);
            float acc = 0.f;
#pragma unroll
            for (int j = 0; j < 16; ++j) {
                const float4 a = y4[j], ww = w4[j];
                acc += a.x * ww.x + a.y * ww.y + a.z * ww.z + a.w * ww.w;
            }
            ytil_s[n] = acc;
            xs_s[n]   = x[b * NIN + n] * s;
        }
        __syncthreads();

        // ---- phase 2: 16 m x 16 n-groups, 32 iters/thread
        const int   ml = tid & (MTILE - 1);
        const int   g  = tid >> 4;
        const float tm = t[b * NOUT + mt * MTILE + ml] * s;
        const float* __restrict__ xp = xs_s   + g * NPER;
        const float* __restrict__ yp = ytil_s + g * NPER;
        float a0 = 0.f, a1 = 0.f, a2 = 0.f, a3 = 0.f;
#pragma unroll
        for (int n = 0; n < NPER; n += 4) {   // 4 accumulators: exp-latency ILP
            const float d0 = xp[n + 0] - tm;
            const float d1 = xp[n + 1] - tm;
            const float d2 = xp[n + 2] - tm;
            const float d3 = xp[n + 3] - tm;
            a0 += __builtin_amdgcn_exp2f(-(d0 * d0)) * yp[n + 0];
            a1 += __builtin_amdgcn_exp2f(-(d1 * d1)) * yp[n + 1];
            a2 += __builtin_amdgcn_exp2f(-(d2 * d2)) * yp[n + 2];
            a3 += __builtin_amdgcn_exp2f(-(d3 * d3)) * yp[n + 3];
        }
        float p = (a0 + a1) + (a2 + a3);
        // combine the wave's 4 n-groups (lane = g_local*16 + ml)
        p += __shfl_xor(p, 16, 64);
        p += __shfl_xor(p, 32, 64);
        if (lane < 16) red[wv * 16 + lane] = p;
        __syncthreads();
        if (tid < 16) {
            const float r = (red[tid] + red[16 + tid]) +
                            (red[32 + tid] + red[48 + tid]) + bias[0];
            out[b * NOUT + mt * MTILE + tid] = r;
        }
    } else {
        // ---- general per-channel path: lane = c; wave wv covers 4 m's
        const float kc2 = -0.72134752f * __expf(-2.0f * sigma[lane]);
        const float wc  = w[lane];
        const float* __restrict__ xb = x + b * NIN;
        const float* __restrict__ yb = y + (size_t)b * NIN * CC + lane;
        for (int j = 0; j < 4; ++j) {
            const int   mm = mt * MTILE + wv * 4 + j;
            const float tm = t[b * NOUT + mm];
            float acc = 0.f;
            for (int n = 0; n < NIN; ++n) {
                const float d = xb[n] - tm;
                acc += __builtin_amdgcn_exp2f(d * d * kc2) * yb[(size_t)n * CC];
            }
            float p = acc * wc;
#pragma unroll
            for (int off = 32; off > 0; off >>= 1) p += __shfl_xor(p, off, 64);
            if (lane == 0) out[b * NOUT + mm] = p + bias[0];
        }
    }
}

extern "C" void kernel_launch(void* const* d_in, const int* in_sizes, int n_in,
                              void* d_out, int out_size, void* d_ws, size_t ws_size,
                              hipStream_t stream) {
    const float* x     = (const float*)d_in[0];
    const float* y     = (const float*)d_in[1];
    const float* t     = (const float*)d_in[2];
    const float* sigma = (const float*)d_in[3];
    const float* w     = (const float*)d_in[4];
    const float* bias  = (const float*)d_in[5];
    float* out = (float*)d_out;

    rbf_fused<<<Bb * MBLKS, 256, 0, stream>>>(x, y, t, sigma, w, bias, out);
}